// Round 1
// baseline (19929.533 us; speedup 1.0000x reference)
//
#include <hip/hip_runtime.h>
#include <hip/hip_bf16.h>
#include <math.h>

#define SEQ 512
#define BATCH 64
#define HID 1024
#define G3 3072
#define LAYERS 3
#define CH 128
#define NCHUNK (SEQ / CH)
#define NWG 64
#define JW 16

typedef __bf16 bf16;
typedef __bf16 bf16x8 __attribute__((ext_vector_type(8)));
typedef float f32x4 __attribute__((ext_vector_type(4)));

static __device__ inline bf16x8 cvt_bf8(f32x4 a, f32x4 b) {
  bf16x8 r;
  r[0] = (bf16)a[0]; r[1] = (bf16)a[1]; r[2] = (bf16)a[2]; r[3] = (bf16)a[3];
  r[4] = (bf16)b[0]; r[5] = (bf16)b[1]; r[6] = (bf16)b[2]; r[7] = (bf16)b[3];
  return r;
}

// gi = X @ Wih^T + bih   -> bf16 [CH*BATCH, 3072]
// X is fp32 (layer 0) or bf16 (layer outputs). Both row-major [rows, 1024].
__global__ __launch_bounds__(256) void gi_gemm(
    const float* __restrict__ Xf, const bf16* __restrict__ Xb, int x_is_f32,
    const float* __restrict__ W,      // [3072,1024] layer slice, fp32
    const float* __restrict__ bih,    // [3072] layer slice
    bf16* __restrict__ gi)
{
  const int tid  = threadIdx.x;
  const int lane = tid & 63, wave = tid >> 6;
  const int quad = lane >> 4, l16 = lane & 15;
  const int m_wave = blockIdx.x * 128 + (wave & 1) * 64;
  const int n_wave = blockIdx.y * 128 + (wave >> 1) * 64;

  f32x4 acc[4][4];
#pragma unroll
  for (int i = 0; i < 4; i++)
#pragma unroll
    for (int j = 0; j < 4; j++) acc[i][j] = (f32x4)(0.0f);

  for (int k0 = 0; k0 < HID; k0 += 32) {
    const int kk = k0 + quad * 8;
    bf16x8 a[4], b[4];
#pragma unroll
    for (int i = 0; i < 4; i++) {
      const int row = m_wave + i * 16 + l16;
      if (x_is_f32) {
        const float* p = Xf + row * HID + kk;
        f32x4 u0 = *(const f32x4*)p;
        f32x4 u1 = *(const f32x4*)(p + 4);
        a[i] = cvt_bf8(u0, u1);
      } else {
        a[i] = *(const bf16x8*)(Xb + row * HID + kk);
      }
    }
#pragma unroll
    for (int j = 0; j < 4; j++) {
      const int row = n_wave + j * 16 + l16;
      const float* p = W + row * HID + kk;
      f32x4 u0 = *(const f32x4*)p;
      f32x4 u1 = *(const f32x4*)(p + 4);
      b[j] = cvt_bf8(u0, u1);
    }
#pragma unroll
    for (int i = 0; i < 4; i++)
#pragma unroll
      for (int j = 0; j < 4; j++)
        acc[i][j] = __builtin_amdgcn_mfma_f32_16x16x32_bf16(a[i], b[j], acc[i][j], 0, 0, 0);
  }

#pragma unroll
  for (int i = 0; i < 4; i++) {
#pragma unroll
    for (int j = 0; j < 4; j++) {
      const int n = n_wave + j * 16 + l16;
      const float bias = bih[n];
#pragma unroll
      for (int r = 0; r < 4; r++) {
        const int m = m_wave + i * 16 + quad * 4 + r;
        gi[(long)m * G3 + n] = (bf16)(acc[i][j][r] + bias);
      }
    }
  }
}

// Persistent recurrent chunk: 64 WGs, each owns hidden slice j0..j0+15 (rows
// {j, H+j, 2H+j} of Whh as register-resident bf16 A-frags). Waves partition K.
// Per-step sync: monotonic per-WG flags (agent scope), double-buffered h (bf16).
__global__ __launch_bounds__(256, 1) void gru_chunk(
    const float* __restrict__ Whh,    // [3072,1024] layer slice
    const float* __restrict__ bhh,    // [3072] layer slice
    const bf16*  __restrict__ gi,     // [CH*BATCH, 3072]
    const float* __restrict__ h0l,    // [BATCH, HID] layer slice of h0
    bf16*  __restrict__ out_bf,       // chunk base (layers 0,1)
    float* __restrict__ out_f32,      // chunk base (layer 2 -> d_out)
    int write_f32,
    bf16*  __restrict__ h_buf,        // [2][BATCH][HID]
    float* __restrict__ h_master,     // [BATCH][HID] fp32 state carry
    int*   __restrict__ flags,        // [NWG]
    int t0, int flag_base)
{
  const int wg   = blockIdx.x;
  const int j0   = wg * JW;
  const int tid  = threadIdx.x;
  const int lane = tid & 63, wave = tid >> 6;
  const int quad = lane >> 4, l16 = lane & 15;
  const int kr   = wave * 256;   // this wave's K range [kr, kr+256)

  __shared__ float part[4][3][4][16][17];  // [wave][gate][ntile][row][col(+pad)]
  __shared__ float h_loc[BATCH][JW];       // fp32 local h slice
  __shared__ float bhh_s[3][JW];

  // ---- prologue: weights -> register A-frags (stay for whole chunk) ----
  bf16x8 afr[3][8];
#pragma unroll
  for (int g = 0; g < 3; g++) {
    const int row = g * HID + j0 + l16;
    const float* wp = Whh + (long)row * HID + kr + quad * 8;
#pragma unroll
    for (int t = 0; t < 8; t++) {
      f32x4 u0 = *(const f32x4*)(wp + t * 32);
      f32x4 u1 = *(const f32x4*)(wp + t * 32 + 4);
      afr[g][t] = cvt_bf8(u0, u1);
    }
  }
  if (tid < 3 * JW) {
    const int g = tid / JW, j = tid % JW;
    bhh_s[g][j] = bhh[g * HID + j0 + j];
  }

  if (t0 == 0) {
    for (int e = tid; e < JW * BATCH; e += 256) {
      const int j = e & 15, b = e >> 4;
      const float v = h0l[b * HID + j0 + j];
      h_loc[b][j] = v;
      h_buf[b * HID + j0 + j] = (bf16)v;   // parity 0
    }
  } else {
    for (int e = tid; e < JW * BATCH; e += 256) {
      const int j = e & 15, b = e >> 4;
      h_loc[b][j] = h_master[b * HID + j0 + j];
    }
  }
  __syncthreads();
  if (tid == 0) {
    __threadfence();
    __hip_atomic_store(&flags[wg], flag_base, __ATOMIC_RELEASE, __HIP_MEMORY_SCOPE_AGENT);
  }

  for (int s = 0; s < CH; s++) {
    const int tpar = (t0 + s) & 1;

    if (tid < NWG) {
      const int target = flag_base + s;
      while (__hip_atomic_load(&flags[tid], __ATOMIC_ACQUIRE, __HIP_MEMORY_SCOPE_AGENT) < target)
        __builtin_amdgcn_s_sleep(1);
    }
    __syncthreads();  // flags passed; also fences prior iter's LDS reads

    // ---- partial gh over this wave's K range ----
    const bf16* hb = h_buf + tpar * BATCH * HID;
    f32x4 acc[3][4];
#pragma unroll
    for (int g = 0; g < 3; g++)
#pragma unroll
      for (int nt = 0; nt < 4; nt++) acc[g][nt] = (f32x4)(0.0f);

#pragma unroll
    for (int t = 0; t < 8; t++) {
      bf16x8 bfr[4];
#pragma unroll
      for (int nt = 0; nt < 4; nt++) {
        const int b = nt * 16 + l16;
        bfr[nt] = *(const bf16x8*)(hb + b * HID + kr + t * 32 + quad * 8);
      }
#pragma unroll
      for (int g = 0; g < 3; g++)
#pragma unroll
        for (int nt = 0; nt < 4; nt++)
          acc[g][nt] = __builtin_amdgcn_mfma_f32_16x16x32_bf16(afr[g][t], bfr[nt], acc[g][nt], 0, 0, 0);
    }

#pragma unroll
    for (int g = 0; g < 3; g++)
#pragma unroll
      for (int nt = 0; nt < 4; nt++)
#pragma unroll
        for (int r = 0; r < 4; r++)
          part[wave][g][nt][quad * 4 + r][l16] = acc[g][nt][r];
    __syncthreads();

    // ---- reduce across waves + gates + state update ----
    const bf16* gi_s = gi + (long)s * BATCH * G3;
    bf16* hnext = h_buf + (tpar ^ 1) * BATCH * HID;
    for (int e = tid; e < JW * BATCH; e += 256) {
      const int j = e & 15, b = e >> 4;
      const int nt = b >> 4, bl = b & 15;
      float ghr = 0.f, ghz = 0.f, ghn = 0.f;
#pragma unroll
      for (int w = 0; w < 4; w++) {
        ghr += part[w][0][nt][j][bl];
        ghz += part[w][1][nt][j][bl];
        ghn += part[w][2][nt][j][bl];
      }
      ghr += bhh_s[0][j];
      ghz += bhh_s[1][j];
      ghn += bhh_s[2][j];
      const bf16* gp = gi_s + (long)b * G3 + j0 + j;
      const float gir = (float)gp[0];
      const float giz = (float)gp[HID];
      const float gin = (float)gp[2 * HID];
      const float r = 1.f / (1.f + __expf(-(gir + ghr)));
      const float z = 1.f / (1.f + __expf(-(giz + ghz)));
      const float nn = tanhf(gin + r * ghn);
      const float hp = h_loc[b][j];
      const float hn = (1.f - z) * nn + z * hp;
      h_loc[b][j] = hn;
      const bf16 hb16 = (bf16)hn;
      hnext[b * HID + j0 + j] = hb16;
      const long oidx = ((long)s * BATCH + b) * HID + j0 + j;
      if (write_f32) out_f32[oidx] = hn;
      else           out_bf[oidx]  = hb16;
    }
    __syncthreads();  // all h_buf writes issued & drained (barrier waits vmcnt)
    if (tid == 0) {
      __hip_atomic_store(&flags[wg], flag_base + s + 1, __ATOMIC_RELEASE, __HIP_MEMORY_SCOPE_AGENT);
    }
  }

  // carry fp32 state to next chunk launch
  for (int e = tid; e < JW * BATCH; e += 256) {
    const int j = e & 15, b = e >> 4;
    h_master[b * HID + j0 + j] = h_loc[b][j];
  }
}

extern "C" void kernel_launch(void* const* d_in, const int* in_sizes, int n_in,
                              void* d_out, int out_size, void* d_ws, size_t ws_size,
                              hipStream_t stream) {
  const float* x   = (const float*)d_in[0];  // [512,64,1024]
  const float* h0  = (const float*)d_in[1];  // [3,64,1024]
  const float* wih = (const float*)d_in[2];  // [9216,1024]
  const float* whh = (const float*)d_in[3];  // [9216,1024]
  const float* bih = (const float*)d_in[4];  // [9216]
  const float* bhh = (const float*)d_in[5];  // [9216]
  float* out = (float*)d_out;                // [512,64,1024] fp32

  char* ws = (char*)d_ws;
  size_t off = 0;
  bf16* gi_buf = (bf16*)(ws + off); off += (size_t)CH * BATCH * G3 * sizeof(bf16);   // 50.3 MB
  bf16* out_bf = (bf16*)(ws + off); off += (size_t)SEQ * BATCH * HID * sizeof(bf16); // 67.1 MB
  bf16* h_buf  = (bf16*)(ws + off); off += (size_t)2 * BATCH * HID * sizeof(bf16);
  float* h_master = (float*)(ws + off); off += (size_t)BATCH * HID * sizeof(float);
  int* flags = (int*)(ws + off); off += 256;

  hipMemsetAsync(flags, 0, 256, stream);

  for (int l = 0; l < LAYERS; l++) {
    const float* Wih_l = wih + (size_t)l * G3 * HID;
    const float* Whh_l = whh + (size_t)l * G3 * HID;
    const float* bih_l = bih + (size_t)l * G3;
    const float* bhh_l = bhh + (size_t)l * G3;
    for (int c = 0; c < NCHUNK; c++) {
      const int t0 = c * CH;
      const float* Xf = (l == 0) ? (x + (size_t)t0 * BATCH * HID) : nullptr;
      const bf16*  Xb = (l == 0) ? nullptr : (out_bf + (size_t)t0 * BATCH * HID);
      dim3 gg(CH * BATCH / 128, G3 / 128);
      gi_gemm<<<gg, 256, 0, stream>>>(Xf, Xb, (l == 0) ? 1 : 0, Wih_l, bih_l, gi_buf);

      const int flag_base = (l * NCHUNK + c) * (CH + 1) + 1;
      gru_chunk<<<NWG, 256, 0, stream>>>(
          Whh_l, bhh_l, gi_buf, h0 + (size_t)l * BATCH * HID,
          out_bf + (size_t)t0 * BATCH * HID,
          out + (size_t)t0 * BATCH * HID,
          (l == LAYERS - 1) ? 1 : 0,
          h_buf, h_master, flags, t0, flag_base);
    }
  }
}

// Round 2
// 16306.219 us; speedup vs baseline: 1.2222x; 1.2222x over previous
//
#include <hip/hip_runtime.h>
#include <hip/hip_bf16.h>
#include <math.h>

#define SEQ 512
#define BATCH 64
#define HID 1024
#define G3 3072
#define LAYERS 3
#define JW 16     // hidden dims owned per WG
#define NWGL 64   // WGs per layer group

typedef __bf16 bf16;
typedef __bf16 bf16x8 __attribute__((ext_vector_type(8)));
typedef float f32x4 __attribute__((ext_vector_type(4)));

static __device__ inline bf16x8 cvt_bf8(f32x4 a, f32x4 b) {
  bf16x8 r;
  r[0] = (bf16)a[0]; r[1] = (bf16)a[1]; r[2] = (bf16)a[2]; r[3] = (bf16)a[3];
  r[4] = (bf16)b[0]; r[5] = (bf16)b[1]; r[6] = (bf16)b[2]; r[7] = (bf16)b[3];
  return r;
}

__global__ __launch_bounds__(256) void x_to_bf16(const float* __restrict__ x,
                                                 bf16* __restrict__ xb) {
  const size_t i = ((size_t)blockIdx.x * 256 + threadIdx.x) * 8;
  f32x4 u0 = *(const f32x4*)(x + i);
  f32x4 u1 = *(const f32x4*)(x + i + 4);
  *(bf16x8*)(xb + i) = cvt_bf8(u0, u1);
}

// Persistent pipelined GRU: 192 WGs = 3 layer-groups x 64. Each WG owns 16
// hidden dims of its layer; both Wih and Whh slices live in registers.
// Per step: gi (input-side) and gh (hidden-side) both computed via MFMA on
// the fly. Layer l+1 consumes layer l's step-s output through the same
// double-buffered h broadcast used for the recurrence (wavefront pipeline).
__global__ __launch_bounds__(256, 1) void gru_persist(
    const bf16*  __restrict__ xb,    // [SEQ][BATCH][HID]
    const float* __restrict__ h0,    // [LAYERS][BATCH][HID]
    const float* __restrict__ wih,   // [LAYERS*G3][HID]
    const float* __restrict__ whh,   // [LAYERS*G3][HID]
    const float* __restrict__ bih,   // [LAYERS*G3]
    const float* __restrict__ bhh,   // [LAYERS*G3]
    float* __restrict__ out,         // [SEQ][BATCH][HID]
    bf16*  __restrict__ hbuf,        // [LAYERS][2][BATCH][HID]
    int*   __restrict__ flags)       // [LAYERS*NWGL], monotonic
{
  const int l    = blockIdx.x >> 6;
  const int wg   = blockIdx.x & 63;
  const int j0   = wg * JW;
  const int tid  = threadIdx.x;
  const int lane = tid & 63, wave = tid >> 6;
  const int quad = lane >> 4, l16 = lane & 15;
  const int kr   = wave * 256;   // this wave's K range

  __shared__ float part[4][3][4][16][17];  // 52224 B: [wave][plane][nt][row][col+pad]
  __shared__ float h_loc[BATCH][JW];       // fp32 hidden-state carry
  __shared__ float bI[3][JW], bH[3][JW];

  // ---- prologue: both weight slices -> register A-fragments ----
  const float* WhhL = whh + (size_t)l * G3 * HID;
  const float* WihL = wih + (size_t)l * G3 * HID;
  bf16x8 aH[3][8], aI[3][8];
#pragma unroll
  for (int g = 0; g < 3; g++) {
    const int row = g * HID + j0 + l16;
    const float* ph = WhhL + (size_t)row * HID + kr + quad * 8;
    const float* pi = WihL + (size_t)row * HID + kr + quad * 8;
#pragma unroll
    for (int t = 0; t < 8; t++) {
      f32x4 h0v = *(const f32x4*)(ph + t * 32);
      f32x4 h1v = *(const f32x4*)(ph + t * 32 + 4);
      aH[g][t] = cvt_bf8(h0v, h1v);
      f32x4 i0v = *(const f32x4*)(pi + t * 32);
      f32x4 i1v = *(const f32x4*)(pi + t * 32 + 4);
      aI[g][t] = cvt_bf8(i0v, i1v);
    }
  }
  if (tid < 48) {
    const int g = tid >> 4, j = tid & 15;
    bI[g][j] = bih[l * G3 + g * HID + j0 + j];
    bH[g][j] = bhh[l * G3 + g * HID + j0 + j];
  }
  for (int e = tid; e < JW * BATCH; e += 256) {
    const int j = e & 15, b = e >> 4;
    const float v = h0[((size_t)l * BATCH + b) * HID + j0 + j];
    h_loc[b][j] = v;
    hbuf[((size_t)(l * 2 + 0) * BATCH + b) * HID + j0 + j] = (bf16)v;  // parity 0
  }
  __syncthreads();
  if (tid == 0)
    __hip_atomic_store(&flags[blockIdx.x], 1, __ATOMIC_RELEASE, __HIP_MEMORY_SCOPE_AGENT);

  for (int s = 0; s < SEQ; s++) {
    // ---- wait: self group >= s+1; upstream >= s+2; downstream >= s ----
    if (tid < 3 * NWGL) {
      const int gt = tid >> 6;
      int target = -1;
      if (gt == l)          target = s + 1;   // peers done step s-1 (h ready)
      else if (gt == l - 1) target = s + 2;   // upstream done step s (input ready)
      else if (gt == l + 1) target = s;       // consumer drained step s-2 (slot free)
      if (target > 0) {
        while (__hip_atomic_load(&flags[tid], __ATOMIC_ACQUIRE, __HIP_MEMORY_SCOPE_AGENT) < target)
          __builtin_amdgcn_s_sleep(1);
      }
    }
    __syncthreads();

    const bf16* hB  = hbuf + (size_t)(l * 2 + (s & 1)) * BATCH * HID;
    const bf16* inB = (l == 0)
        ? (xb + (size_t)s * BATCH * HID)
        : (hbuf + (size_t)((l - 1) * 2 + ((s + 1) & 1)) * BATCH * HID);

    // ---- MFMA: r,z combined (gi+gh); n kept split ----
    f32x4 aR[4], aZ[4], aGN[4], aIN[4];
#pragma unroll
    for (int nt = 0; nt < 4; nt++) {
      aR[nt] = (f32x4)(0.0f); aZ[nt] = (f32x4)(0.0f);
      aGN[nt] = (f32x4)(0.0f); aIN[nt] = (f32x4)(0.0f);
    }
#pragma unroll
    for (int t = 0; t < 8; t++) {
      bf16x8 bh4[4];
#pragma unroll
      for (int nt = 0; nt < 4; nt++)
        bh4[nt] = *(const bf16x8*)(hB + (size_t)(nt * 16 + l16) * HID + kr + t * 32 + quad * 8);
#pragma unroll
      for (int nt = 0; nt < 4; nt++) {
        aR[nt]  = __builtin_amdgcn_mfma_f32_16x16x32_bf16(aH[0][t], bh4[nt], aR[nt], 0, 0, 0);
        aZ[nt]  = __builtin_amdgcn_mfma_f32_16x16x32_bf16(aH[1][t], bh4[nt], aZ[nt], 0, 0, 0);
        aGN[nt] = __builtin_amdgcn_mfma_f32_16x16x32_bf16(aH[2][t], bh4[nt], aGN[nt], 0, 0, 0);
      }
    }
#pragma unroll
    for (int t = 0; t < 8; t++) {
      bf16x8 bx4[4];
#pragma unroll
      for (int nt = 0; nt < 4; nt++)
        bx4[nt] = *(const bf16x8*)(inB + (size_t)(nt * 16 + l16) * HID + kr + t * 32 + quad * 8);
#pragma unroll
      for (int nt = 0; nt < 4; nt++) {
        aR[nt]  = __builtin_amdgcn_mfma_f32_16x16x32_bf16(aI[0][t], bx4[nt], aR[nt], 0, 0, 0);
        aZ[nt]  = __builtin_amdgcn_mfma_f32_16x16x32_bf16(aI[1][t], bx4[nt], aZ[nt], 0, 0, 0);
        aIN[nt] = __builtin_amdgcn_mfma_f32_16x16x32_bf16(aI[2][t], bx4[nt], aIN[nt], 0, 0, 0);
      }
    }

    // ---- phase 1: store r,z,gh_n partials; reduce across waves ----
#pragma unroll
    for (int nt = 0; nt < 4; nt++)
#pragma unroll
      for (int r = 0; r < 4; r++) {
        part[wave][0][nt][quad * 4 + r][l16] = aR[nt][r];
        part[wave][1][nt][quad * 4 + r][l16] = aZ[nt][r];
        part[wave][2][nt][quad * 4 + r][l16] = aGN[nt][r];
      }
    __syncthreads();
    float rp[4], zp[4], gnp[4];
#pragma unroll
    for (int u = 0; u < 4; u++) {
      const int e = tid + u * 256;
      const int j = e & 15, b = e >> 4;
      const int nt = b >> 4, bl = b & 15;
      float sr = 0.f, sz = 0.f, sn = 0.f;
#pragma unroll
      for (int w = 0; w < 4; w++) {
        sr += part[w][0][nt][j][bl];
        sz += part[w][1][nt][j][bl];
        sn += part[w][2][nt][j][bl];
      }
      rp[u] = sr; zp[u] = sz; gnp[u] = sn;
    }
    __syncthreads();

    // ---- phase 2: gi_n partials (reuse plane 0) ----
#pragma unroll
    for (int nt = 0; nt < 4; nt++)
#pragma unroll
      for (int r = 0; r < 4; r++)
        part[wave][0][nt][quad * 4 + r][l16] = aIN[nt][r];
    __syncthreads();

    bf16* hOut = hbuf + (size_t)(l * 2 + ((s + 1) & 1)) * BATCH * HID;
#pragma unroll
    for (int u = 0; u < 4; u++) {
      const int e = tid + u * 256;
      const int j = e & 15, b = e >> 4;
      const int nt = b >> 4, bl = b & 15;
      float gin = 0.f;
#pragma unroll
      for (int w = 0; w < 4; w++) gin += part[w][0][nt][j][bl];
      const float r = 1.f / (1.f + __expf(-(rp[u] + bI[0][j] + bH[0][j])));
      const float z = 1.f / (1.f + __expf(-(zp[u] + bI[1][j] + bH[1][j])));
      const float n = tanhf(gin + bI[2][j] + r * (gnp[u] + bH[2][j]));
      const float hp = h_loc[b][j];
      const float hn = (1.f - z) * n + z * hp;
      h_loc[b][j] = hn;
      hOut[(size_t)b * HID + j0 + j] = (bf16)hn;
      if (l == 2) out[((size_t)s * BATCH + b) * HID + j0 + j] = hn;
    }
    __syncthreads();  // barrier drains all stores (vmcnt) before flag release
    if (tid == 0)
      __hip_atomic_store(&flags[blockIdx.x], s + 2, __ATOMIC_RELEASE, __HIP_MEMORY_SCOPE_AGENT);
  }
}

extern "C" void kernel_launch(void* const* d_in, const int* in_sizes, int n_in,
                              void* d_out, int out_size, void* d_ws, size_t ws_size,
                              hipStream_t stream) {
  const float* x   = (const float*)d_in[0];
  const float* h0  = (const float*)d_in[1];
  const float* wih = (const float*)d_in[2];
  const float* whh = (const float*)d_in[3];
  const float* bih = (const float*)d_in[4];
  const float* bhh = (const float*)d_in[5];
  float* out = (float*)d_out;

  char* ws = (char*)d_ws;
  size_t off = 0;
  bf16* xb   = (bf16*)(ws + off); off += (size_t)SEQ * BATCH * HID * sizeof(bf16);        // 67 MB
  bf16* hbuf = (bf16*)(ws + off); off += (size_t)LAYERS * 2 * BATCH * HID * sizeof(bf16); // 768 KB
  int* flags = (int*)(ws + off);  off += 1024;

  hipMemsetAsync(flags, 0, 1024, stream);
  x_to_bf16<<<(SEQ * BATCH * HID) / (256 * 8), 256, 0, stream>>>(x, xb);
  gru_persist<<<LAYERS * NWGL, 256, 0, stream>>>(xb, h0, wih, whh, bih, bhh,
                                                 out, hbuf, flags);
}

// Round 3
// 14025.581 us; speedup vs baseline: 1.4209x; 1.1626x over previous
//
#include <hip/hip_runtime.h>
#include <hip/hip_bf16.h>
#include <math.h>

#define SEQ 512
#define BATCH 64
#define HID 1024
#define G3 3072
#define LAYERS 3
#define JW 16     // hidden dims owned per WG
#define NWGL 64   // WGs per layer group

typedef __bf16 bf16;
typedef __bf16 bf16x8 __attribute__((ext_vector_type(8)));
typedef float f32x4 __attribute__((ext_vector_type(4)));

static __device__ inline bf16x8 cvt_bf8(f32x4 a, f32x4 b) {
  bf16x8 r;
  r[0] = (bf16)a[0]; r[1] = (bf16)a[1]; r[2] = (bf16)a[2]; r[3] = (bf16)a[3];
  r[4] = (bf16)b[0]; r[5] = (bf16)b[1]; r[6] = (bf16)b[2]; r[7] = (bf16)b[3];
  return r;
}

__global__ __launch_bounds__(256) void x_to_bf16(const float* __restrict__ x,
                                                 bf16* __restrict__ xb) {
  const size_t i = ((size_t)blockIdx.x * 256 + threadIdx.x) * 8;
  f32x4 u0 = *(const f32x4*)(x + i);
  f32x4 u1 = *(const f32x4*)(x + i + 4);
  *(bf16x8*)(xb + i) = cvt_bf8(u0, u1);
}

// Persistent pipelined GRU: 192 WGs = 3 layer-groups x 64.
// Sync protocol (the R3 fix): spin on RELAXED agent atomic loads (coherent by
// themselves, no per-iteration buffer_inv), then ONE acquire fence per phase.
// Release: fence(RELEASE, agent) once (wbl2 flushes this step's h stores),
// then relaxed flag store. Split wait: h-side work runs before the upstream
// flag is needed, hiding inter-layer flag propagation latency.
__global__ __launch_bounds__(256, 1) void gru_persist(
    const bf16*  __restrict__ xb,    // [SEQ][BATCH][HID]
    const float* __restrict__ h0,    // [LAYERS][BATCH][HID]
    const float* __restrict__ wih,   // [LAYERS*G3][HID]
    const float* __restrict__ whh,   // [LAYERS*G3][HID]
    const float* __restrict__ bih,   // [LAYERS*G3]
    const float* __restrict__ bhh,   // [LAYERS*G3]
    float* __restrict__ out,         // [SEQ][BATCH][HID]
    bf16*  __restrict__ hbuf,        // [LAYERS][2][BATCH][HID]
    int*   __restrict__ flags)       // [LAYERS*NWGL], monotonic
{
  const int l    = blockIdx.x >> 6;
  const int wg   = blockIdx.x & 63;
  const int j0   = wg * JW;
  const int tid  = threadIdx.x;
  const int lane = tid & 63, wave = tid >> 6;
  const int quad = lane >> 4, l16 = lane & 15;
  const int kr   = wave * 256;   // this wave's K range

  __shared__ float part[4][3][4][16][17];  // [wave][plane][nt][row][col+pad]
  __shared__ float h_loc[BATCH][JW];       // fp32 hidden-state carry
  __shared__ float bI[3][JW], bH[3][JW];

  // ---- prologue: both weight slices -> register A-fragments ----
  const float* WhhL = whh + (size_t)l * G3 * HID;
  const float* WihL = wih + (size_t)l * G3 * HID;
  bf16x8 aH[3][8], aI[3][8];
#pragma unroll
  for (int g = 0; g < 3; g++) {
    const int row = g * HID + j0 + l16;
    const float* ph = WhhL + (size_t)row * HID + kr + quad * 8;
    const float* pi = WihL + (size_t)row * HID + kr + quad * 8;
#pragma unroll
    for (int t = 0; t < 8; t++) {
      f32x4 h0v = *(const f32x4*)(ph + t * 32);
      f32x4 h1v = *(const f32x4*)(ph + t * 32 + 4);
      aH[g][t] = cvt_bf8(h0v, h1v);
      f32x4 i0v = *(const f32x4*)(pi + t * 32);
      f32x4 i1v = *(const f32x4*)(pi + t * 32 + 4);
      aI[g][t] = cvt_bf8(i0v, i1v);
    }
  }
  if (tid < 48) {
    const int g = tid >> 4, j = tid & 15;
    bI[g][j] = bih[l * G3 + g * HID + j0 + j];
    bH[g][j] = bhh[l * G3 + g * HID + j0 + j];
  }
  for (int e = tid; e < JW * BATCH; e += 256) {
    const int j = e & 15, b = e >> 4;
    const float v = h0[((size_t)l * BATCH + b) * HID + j0 + j];
    h_loc[b][j] = v;
    hbuf[((size_t)(l * 2 + 0) * BATCH + b) * HID + j0 + j] = (bf16)v;  // parity 0
  }
  __syncthreads();
  if (tid == 0) {
    __builtin_amdgcn_fence(__ATOMIC_RELEASE, "agent");
    __hip_atomic_store(&flags[blockIdx.x], 1, __ATOMIC_RELAXED, __HIP_MEMORY_SCOPE_AGENT);
  }

  for (int s = 0; s < SEQ; s++) {
    // ---- phase-1 wait: peers >= s+1 (h ready), downstream >= s (slot free) --
    if (tid < 3 * NWGL) {
      const int gt = tid >> 6;
      int target = -1;
      if (gt == l)          target = s + 1;
      else if (gt == l + 1) target = s;
      if (target > 0) {
        while (__hip_atomic_load(&flags[tid], __ATOMIC_RELAXED, __HIP_MEMORY_SCOPE_AGENT) < target)
          __builtin_amdgcn_s_sleep(1);
      }
    }
    __syncthreads();
    __builtin_amdgcn_fence(__ATOMIC_ACQUIRE, "agent");

    const bf16* hB = hbuf + (size_t)(l * 2 + (s & 1)) * BATCH * HID;

    // ---- h-side MFMA (does not need upstream) ----
    f32x4 aR[4], aZ[4], aGN[4], aIN[4];
#pragma unroll
    for (int nt = 0; nt < 4; nt++) {
      aR[nt] = (f32x4)(0.0f); aZ[nt] = (f32x4)(0.0f);
      aGN[nt] = (f32x4)(0.0f); aIN[nt] = (f32x4)(0.0f);
    }
#pragma unroll
    for (int t = 0; t < 8; t++) {
      bf16x8 bh4[4];
#pragma unroll
      for (int nt = 0; nt < 4; nt++)
        bh4[nt] = *(const bf16x8*)(hB + (size_t)(nt * 16 + l16) * HID + kr + t * 32 + quad * 8);
#pragma unroll
      for (int nt = 0; nt < 4; nt++) {
        aR[nt]  = __builtin_amdgcn_mfma_f32_16x16x32_bf16(aH[0][t], bh4[nt], aR[nt], 0, 0, 0);
        aZ[nt]  = __builtin_amdgcn_mfma_f32_16x16x32_bf16(aH[1][t], bh4[nt], aZ[nt], 0, 0, 0);
        aGN[nt] = __builtin_amdgcn_mfma_f32_16x16x32_bf16(aH[2][t], bh4[nt], aGN[nt], 0, 0, 0);
      }
    }

    // ---- phase-2 wait (l>0): upstream >= s+2 (step-s input ready) ----
    if (l > 0) {
      if ((tid >> 6) == l - 1) {
        const int target = s + 2;
        while (__hip_atomic_load(&flags[tid], __ATOMIC_RELAXED, __HIP_MEMORY_SCOPE_AGENT) < target)
          __builtin_amdgcn_s_sleep(1);
      }
      __syncthreads();
      __builtin_amdgcn_fence(__ATOMIC_ACQUIRE, "agent");
    }

    const bf16* inB = (l == 0)
        ? (xb + (size_t)s * BATCH * HID)
        : (hbuf + (size_t)((l - 1) * 2 + ((s + 1) & 1)) * BATCH * HID);

#pragma unroll
    for (int t = 0; t < 8; t++) {
      bf16x8 bx4[4];
#pragma unroll
      for (int nt = 0; nt < 4; nt++)
        bx4[nt] = *(const bf16x8*)(inB + (size_t)(nt * 16 + l16) * HID + kr + t * 32 + quad * 8);
#pragma unroll
      for (int nt = 0; nt < 4; nt++) {
        aR[nt]  = __builtin_amdgcn_mfma_f32_16x16x32_bf16(aI[0][t], bx4[nt], aR[nt], 0, 0, 0);
        aZ[nt]  = __builtin_amdgcn_mfma_f32_16x16x32_bf16(aI[1][t], bx4[nt], aZ[nt], 0, 0, 0);
        aIN[nt] = __builtin_amdgcn_mfma_f32_16x16x32_bf16(aI[2][t], bx4[nt], aIN[nt], 0, 0, 0);
      }
    }

    // ---- phase A: r,z,gh_n partials; reduce across waves ----
#pragma unroll
    for (int nt = 0; nt < 4; nt++)
#pragma unroll
      for (int r = 0; r < 4; r++) {
        part[wave][0][nt][quad * 4 + r][l16] = aR[nt][r];
        part[wave][1][nt][quad * 4 + r][l16] = aZ[nt][r];
        part[wave][2][nt][quad * 4 + r][l16] = aGN[nt][r];
      }
    __syncthreads();
    float rp[4], zp[4], gnp[4];
#pragma unroll
    for (int u = 0; u < 4; u++) {
      const int e = tid + u * 256;
      const int j = e & 15, b = e >> 4;
      const int nt = b >> 4, bl = b & 15;
      float sr = 0.f, sz = 0.f, sn = 0.f;
#pragma unroll
      for (int w = 0; w < 4; w++) {
        sr += part[w][0][nt][j][bl];
        sz += part[w][1][nt][j][bl];
        sn += part[w][2][nt][j][bl];
      }
      rp[u] = sr; zp[u] = sz; gnp[u] = sn;
    }
    __syncthreads();

    // ---- phase B: gi_n partials (reuse plane 0) ----
#pragma unroll
    for (int nt = 0; nt < 4; nt++)
#pragma unroll
      for (int r = 0; r < 4; r++)
        part[wave][0][nt][quad * 4 + r][l16] = aIN[nt][r];
    __syncthreads();

    bf16* hOut = hbuf + (size_t)(l * 2 + ((s + 1) & 1)) * BATCH * HID;
#pragma unroll
    for (int u = 0; u < 4; u++) {
      const int e = tid + u * 256;
      const int j = e & 15, b = e >> 4;
      const int nt = b >> 4, bl = b & 15;
      float gin = 0.f;
#pragma unroll
      for (int w = 0; w < 4; w++) gin += part[w][0][nt][j][bl];
      const float r = 1.f / (1.f + __expf(-(rp[u] + bI[0][j] + bH[0][j])));
      const float z = 1.f / (1.f + __expf(-(zp[u] + bI[1][j] + bH[1][j])));
      const float n = tanhf(gin + bI[2][j] + r * (gnp[u] + bH[2][j]));
      const float hp = h_loc[b][j];
      const float hn = (1.f - z) * n + z * hp;
      h_loc[b][j] = hn;
      hOut[(size_t)b * HID + j0 + j] = (bf16)hn;
      if (l == 2) out[((size_t)s * BATCH + b) * HID + j0 + j] = hn;
    }
    __syncthreads();  // drains all waves' stores (vmcnt) before release
    if (tid == 0) {
      __builtin_amdgcn_fence(__ATOMIC_RELEASE, "agent");  // wbl2: h visible at L3
      __hip_atomic_store(&flags[blockIdx.x], s + 2, __ATOMIC_RELAXED, __HIP_MEMORY_SCOPE_AGENT);
    }
  }
}

extern "C" void kernel_launch(void* const* d_in, const int* in_sizes, int n_in,
                              void* d_out, int out_size, void* d_ws, size_t ws_size,
                              hipStream_t stream) {
  const float* x   = (const float*)d_in[0];
  const float* h0  = (const float*)d_in[1];
  const float* wih = (const float*)d_in[2];
  const float* whh = (const float*)d_in[3];
  const float* bih = (const float*)d_in[4];
  const float* bhh = (const float*)d_in[5];
  float* out = (float*)d_out;

  char* ws = (char*)d_ws;
  size_t off = 0;
  bf16* xb   = (bf16*)(ws + off); off += (size_t)SEQ * BATCH * HID * sizeof(bf16);        // 67 MB
  bf16* hbuf = (bf16*)(ws + off); off += (size_t)LAYERS * 2 * BATCH * HID * sizeof(bf16); // 768 KB
  int* flags = (int*)(ws + off);  off += 1024;

  hipMemsetAsync(flags, 0, 1024, stream);
  x_to_bf16<<<(SEQ * BATCH * HID) / (256 * 8), 256, 0, stream>>>(x, xb);
  gru_persist<<<LAYERS * NWGL, 256, 0, stream>>>(xb, h0, wih, whh, bih, bhh,
                                                 out, hbuf, flags);
}

// Round 4
// 13055.554 us; speedup vs baseline: 1.5265x; 1.0743x over previous
//
#include <hip/hip_runtime.h>
#include <hip/hip_bf16.h>
#include <math.h>

#define SEQ 512
#define BATCH 64
#define HID 1024
#define G3 3072
#define LAYERS 3
#define JW 16     // hidden dims owned per WG
#define NWGL 64   // WGs per layer group

typedef __bf16 bf16;
typedef __bf16 bf16x8 __attribute__((ext_vector_type(8)));
typedef float f32x4 __attribute__((ext_vector_type(4)));

static __device__ inline bf16x8 cvt_bf8(f32x4 a, f32x4 b) {
  bf16x8 r;
  r[0] = (bf16)a[0]; r[1] = (bf16)a[1]; r[2] = (bf16)a[2]; r[3] = (bf16)a[3];
  r[4] = (bf16)b[0]; r[5] = (bf16)b[1]; r[6] = (bf16)b[2]; r[7] = (bf16)b[3];
  return r;
}

__global__ __launch_bounds__(256) void x_to_bf16(const float* __restrict__ x,
                                                 bf16* __restrict__ xb) {
  const size_t i = ((size_t)blockIdx.x * 256 + threadIdx.x) * 8;
  f32x4 u0 = *(const f32x4*)(x + i);
  f32x4 u1 = *(const f32x4*)(x + i + 4);
  *(bf16x8*)(xb + i) = cvt_bf8(u0, u1);
}

// Persistent pipelined GRU: 192 WGs = 3 layer-groups x 64.
// R4 sync: per-GROUP monotonic completion counters (atomicAdd on completion),
// ONE polling thread per WG (was 192) -> kills the L3 hot-line contention
// that made flag observation latency dominate the step period.
__global__ __launch_bounds__(256, 1) void gru_persist(
    const bf16*  __restrict__ xb,    // [SEQ][BATCH][HID]
    const float* __restrict__ h0,    // [LAYERS][BATCH][HID]
    const float* __restrict__ wih,   // [LAYERS*G3][HID]
    const float* __restrict__ whh,   // [LAYERS*G3][HID]
    const float* __restrict__ bih,   // [LAYERS*G3]
    const float* __restrict__ bhh,   // [LAYERS*G3]
    float* __restrict__ out,         // [SEQ][BATCH][HID]
    bf16*  __restrict__ hbuf,        // [LAYERS][2][BATCH][HID]
    int*   __restrict__ done)        // [LAYERS] padded x32 ints, monotonic
{
  const int l    = blockIdx.x >> 6;
  const int wg   = blockIdx.x & 63;
  const int j0   = wg * JW;
  const int tid  = threadIdx.x;
  const int lane = tid & 63, wave = tid >> 6;
  const int quad = lane >> 4, l16 = lane & 15;
  const int kr   = wave * 256;   // this wave's K range

  __shared__ float part[4][3][4][16][17];  // [wave][plane][nt][row][col+pad]
  __shared__ float h_loc[BATCH][JW];       // fp32 hidden-state carry
  __shared__ float bI[3][JW], bH[3][JW];

  // ---- prologue: both weight slices -> register A-fragments ----
  const float* WhhL = whh + (size_t)l * G3 * HID;
  const float* WihL = wih + (size_t)l * G3 * HID;
  bf16x8 aH[3][8], aI[3][8];
#pragma unroll
  for (int g = 0; g < 3; g++) {
    const int row = g * HID + j0 + l16;
    const float* ph = WhhL + (size_t)row * HID + kr + quad * 8;
    const float* pi = WihL + (size_t)row * HID + kr + quad * 8;
#pragma unroll
    for (int t = 0; t < 8; t++) {
      f32x4 h0v = *(const f32x4*)(ph + t * 32);
      f32x4 h1v = *(const f32x4*)(ph + t * 32 + 4);
      aH[g][t] = cvt_bf8(h0v, h1v);
      f32x4 i0v = *(const f32x4*)(pi + t * 32);
      f32x4 i1v = *(const f32x4*)(pi + t * 32 + 4);
      aI[g][t] = cvt_bf8(i0v, i1v);
    }
  }
  if (tid < 48) {
    const int g = tid >> 4, j = tid & 15;
    bI[g][j] = bih[l * G3 + g * HID + j0 + j];
    bH[g][j] = bhh[l * G3 + g * HID + j0 + j];
  }
  for (int e = tid; e < JW * BATCH; e += 256) {
    const int j = e & 15, b = e >> 4;
    const float v = h0[((size_t)l * BATCH + b) * HID + j0 + j];
    h_loc[b][j] = v;
    hbuf[((size_t)(l * 2 + 0) * BATCH + b) * HID + j0 + j] = (bf16)v;  // parity 0
  }
  __syncthreads();
  if (tid == 0) {
    __builtin_amdgcn_fence(__ATOMIC_RELEASE, "agent");
    __hip_atomic_fetch_add(&done[l * 32], 1, __ATOMIC_RELAXED, __HIP_MEMORY_SCOPE_AGENT);
  }

  for (int s = 0; s < SEQ; s++) {
    // ---- phase-1 wait: peers completed s-1; downstream drained slot ----
    if (tid == 0) {
      const int pt = 64 * (s + 1);
      while (__hip_atomic_load(&done[l * 32], __ATOMIC_RELAXED, __HIP_MEMORY_SCOPE_AGENT) < pt)
        __builtin_amdgcn_s_sleep(1);
      if (l + 1 < LAYERS && s > 0) {
        const int dt = 64 * s;
        while (__hip_atomic_load(&done[(l + 1) * 32], __ATOMIC_RELAXED, __HIP_MEMORY_SCOPE_AGENT) < dt)
          __builtin_amdgcn_s_sleep(1);
      }
    }
    __syncthreads();
    __builtin_amdgcn_fence(__ATOMIC_ACQUIRE, "agent");

    const bf16* hB = hbuf + (size_t)(l * 2 + (s & 1)) * BATCH * HID;

    // ---- h-side MFMA (does not need upstream) ----
    f32x4 aR[4], aZ[4], aGN[4], aIN[4];
#pragma unroll
    for (int nt = 0; nt < 4; nt++) {
      aR[nt] = (f32x4)(0.0f); aZ[nt] = (f32x4)(0.0f);
      aGN[nt] = (f32x4)(0.0f); aIN[nt] = (f32x4)(0.0f);
    }
#pragma unroll
    for (int t = 0; t < 8; t++) {
      bf16x8 bh4[4];
#pragma unroll
      for (int nt = 0; nt < 4; nt++)
        bh4[nt] = *(const bf16x8*)(hB + (size_t)(nt * 16 + l16) * HID + kr + t * 32 + quad * 8);
#pragma unroll
      for (int nt = 0; nt < 4; nt++) {
        aR[nt]  = __builtin_amdgcn_mfma_f32_16x16x32_bf16(aH[0][t], bh4[nt], aR[nt], 0, 0, 0);
        aZ[nt]  = __builtin_amdgcn_mfma_f32_16x16x32_bf16(aH[1][t], bh4[nt], aZ[nt], 0, 0, 0);
        aGN[nt] = __builtin_amdgcn_mfma_f32_16x16x32_bf16(aH[2][t], bh4[nt], aGN[nt], 0, 0, 0);
      }
    }

    // ---- phase-2 wait (l>0): upstream completed step s ----
    if (l > 0) {
      if (tid == 0) {
        const int ut = 64 * (s + 2);
        while (__hip_atomic_load(&done[(l - 1) * 32], __ATOMIC_RELAXED, __HIP_MEMORY_SCOPE_AGENT) < ut)
          __builtin_amdgcn_s_sleep(1);
      }
      __syncthreads();
      __builtin_amdgcn_fence(__ATOMIC_ACQUIRE, "agent");
    }

    const bf16* inB = (l == 0)
        ? (xb + (size_t)s * BATCH * HID)
        : (hbuf + (size_t)((l - 1) * 2 + ((s + 1) & 1)) * BATCH * HID);

#pragma unroll
    for (int t = 0; t < 8; t++) {
      bf16x8 bx4[4];
#pragma unroll
      for (int nt = 0; nt < 4; nt++)
        bx4[nt] = *(const bf16x8*)(inB + (size_t)(nt * 16 + l16) * HID + kr + t * 32 + quad * 8);
#pragma unroll
      for (int nt = 0; nt < 4; nt++) {
        aR[nt]  = __builtin_amdgcn_mfma_f32_16x16x32_bf16(aI[0][t], bx4[nt], aR[nt], 0, 0, 0);
        aZ[nt]  = __builtin_amdgcn_mfma_f32_16x16x32_bf16(aI[1][t], bx4[nt], aZ[nt], 0, 0, 0);
        aIN[nt] = __builtin_amdgcn_mfma_f32_16x16x32_bf16(aI[2][t], bx4[nt], aIN[nt], 0, 0, 0);
      }
    }

    // ---- phase A: r,z,gh_n partials; reduce across waves ----
#pragma unroll
    for (int nt = 0; nt < 4; nt++)
#pragma unroll
      for (int r = 0; r < 4; r++) {
        part[wave][0][nt][quad * 4 + r][l16] = aR[nt][r];
        part[wave][1][nt][quad * 4 + r][l16] = aZ[nt][r];
        part[wave][2][nt][quad * 4 + r][l16] = aGN[nt][r];
      }
    __syncthreads();
    float rp[4], zp[4], gnp[4];
#pragma unroll
    for (int u = 0; u < 4; u++) {
      const int e = tid + u * 256;
      const int j = e & 15, b = e >> 4;
      const int nt = b >> 4, bl = b & 15;
      float sr = 0.f, sz = 0.f, sn = 0.f;
#pragma unroll
      for (int w = 0; w < 4; w++) {
        sr += part[w][0][nt][j][bl];
        sz += part[w][1][nt][j][bl];
        sn += part[w][2][nt][j][bl];
      }
      rp[u] = sr; zp[u] = sz; gnp[u] = sn;
    }
    __syncthreads();

    // ---- phase B: gi_n partials (reuse plane 0) ----
#pragma unroll
    for (int nt = 0; nt < 4; nt++)
#pragma unroll
      for (int r = 0; r < 4; r++)
        part[wave][0][nt][quad * 4 + r][l16] = aIN[nt][r];
    __syncthreads();

    bf16* hOut = hbuf + (size_t)(l * 2 + ((s + 1) & 1)) * BATCH * HID;
#pragma unroll
    for (int u = 0; u < 4; u++) {
      const int e = tid + u * 256;
      const int j = e & 15, b = e >> 4;
      const int nt = b >> 4, bl = b & 15;
      float gin = 0.f;
#pragma unroll
      for (int w = 0; w < 4; w++) gin += part[w][0][nt][j][bl];
      const float r = 1.f / (1.f + __expf(-(rp[u] + bI[0][j] + bH[0][j])));
      const float z = 1.f / (1.f + __expf(-(zp[u] + bI[1][j] + bH[1][j])));
      const float n = tanhf(gin + bI[2][j] + r * (gnp[u] + bH[2][j]));
      const float hp = h_loc[b][j];
      const float hn = (1.f - z) * n + z * hp;
      h_loc[b][j] = hn;
      hOut[(size_t)b * HID + j0 + j] = (bf16)hn;
      if (l == 2) out[((size_t)s * BATCH + b) * HID + j0 + j] = hn;
    }
    __syncthreads();  // drains all waves' stores (vmcnt) before release
    if (tid == 0) {
      __builtin_amdgcn_fence(__ATOMIC_RELEASE, "agent");  // wbl2: h visible at L3
      __hip_atomic_fetch_add(&done[l * 32], 1, __ATOMIC_RELAXED, __HIP_MEMORY_SCOPE_AGENT);
    }
  }
}

extern "C" void kernel_launch(void* const* d_in, const int* in_sizes, int n_in,
                              void* d_out, int out_size, void* d_ws, size_t ws_size,
                              hipStream_t stream) {
  const float* x   = (const float*)d_in[0];
  const float* h0  = (const float*)d_in[1];
  const float* wih = (const float*)d_in[2];
  const float* whh = (const float*)d_in[3];
  const float* bih = (const float*)d_in[4];
  const float* bhh = (const float*)d_in[5];
  float* out = (float*)d_out;

  char* ws = (char*)d_ws;
  size_t off = 0;
  bf16* xb   = (bf16*)(ws + off); off += (size_t)SEQ * BATCH * HID * sizeof(bf16);        // 67 MB
  bf16* hbuf = (bf16*)(ws + off); off += (size_t)LAYERS * 2 * BATCH * HID * sizeof(bf16); // 768 KB
  int* done  = (int*)(ws + off);  off += 1024;

  hipMemsetAsync(done, 0, 1024, stream);
  x_to_bf16<<<(SEQ * BATCH * HID) / (256 * 8), 256, 0, stream>>>(x, xb);
  gru_persist<<<LAYERS * NWGL, 256, 0, stream>>>(xb, h0, wih, whh, bih, bhh,
                                                 out, hbuf, done);
}